// Round 3
// baseline (2284.756 us; speedup 1.0000x reference)
//
#include <hip/hip_runtime.h>
#include <stdint.h>

#define NGRAPH 1000

// ---------- helpers ----------
static __device__ __forceinline__ uint32_t pack2_bf16(float a, float b) {
  uint32_t ua = __float_as_uint(a), ub = __float_as_uint(b);
  ua = (ua + 0x7fffu + ((ua >> 16) & 1u)) >> 16;   // RNE
  ub = (ub + 0x7fffu + ((ub >> 16) & 1u)) >> 16;
  return ua | (ub << 16);
}

// ---------- weight transpose: w1t[l][k][d] = w1[l][d][k], w2t likewise ----------
__global__ __launch_bounds__(256) void k_prep(const float* __restrict__ w1,
                                              const float* __restrict__ w2,
                                              float* __restrict__ w1t,
                                              float* __restrict__ w2t) {
  int t = blockIdx.x * 256 + threadIdx.x;
  if (t < 4 * 65 * 32) {
    int l = t / 2080, r = t % 2080, k = r / 32, d = r % 32;
    w1t[t] = w1[l * 2080 + d * 65 + k];
  } else if (t < 4 * 65 * 32 + 4 * 32 * 32) {
    int u = t - 4 * 65 * 32;
    int l = u / 1024, r = u % 1024, k = r / 32, d = r % 32;
    w2t[u] = w2[l * 1024 + d * 32 + k];
  }
}

// ---------- h = x @ Wi^T + bi ----------
__global__ __launch_bounds__(256) void k_init(const float* __restrict__ x,
                                              const float* __restrict__ wi,
                                              const float* __restrict__ bi,
                                              float* __restrict__ h, int N) {
  int t = blockIdx.x * 256 + threadIdx.x;
  if (t >= N * 32) return;
  int n = t >> 5, d = t & 31;
  h[t] = fmaf(x[2 * n], wi[2 * d], fmaf(x[2 * n + 1], wi[2 * d + 1], bi[d]));
}

// ---------- block stats reduction (shared by pass A/B) ----------
static __device__ __forceinline__ void block_stats_reduce(float* ssum, float* ssq,
                                                          float* __restrict__ stats) {
  __shared__ float red[4][64];
  const int lane = threadIdx.x & 63, wv = threadIdx.x >> 6;
#pragma unroll
  for (int q = 0; q < 32; q++) {
    float a = ssum[q], b = ssq[q];
#pragma unroll
    for (int m = 32; m >= 1; m >>= 1) {
      a += __shfl_xor(a, m, 64);
      b += __shfl_xor(b, m, 64);
    }
    if (lane == 0) { red[wv][q] = a; red[wv][32 + q] = b; }
  }
  __syncthreads();
  if (threadIdx.x < 64) {
    int q = threadIdx.x;
    stats[(size_t)blockIdx.x * 64 + q] = red[0][q] + red[1][q] + red[2][q] + red[3][q];
  }
}

// ---------- pass A: m_pre = [h_dst, h_src, ea] @ W1^T + b1 ; stats ----------
__global__ __launch_bounds__(256) void k_gemm1(
    const float* __restrict__ h, const int* __restrict__ src, const int* __restrict__ dst,
    const float* __restrict__ ea, const float* __restrict__ w1t, const float* __restrict__ b1,
    uint32_t* __restrict__ mpre, float* __restrict__ stats, int E) {
  float ssum[32], ssq[32];
#pragma unroll
  for (int q = 0; q < 32; q++) { ssum[q] = 0.f; ssq[q] = 0.f; }
  const int stride = gridDim.x * blockDim.x;
  for (int e = blockIdx.x * blockDim.x + threadIdx.x; e < E; e += stride) {
    const int vd = dst[e], vs = src[e];
    const float eav = ea[e];
    float acc[32];
#pragma unroll
    for (int d = 0; d < 32; d++) acc[d] = fmaf(eav, w1t[64 * 32 + d], b1[d]);
    {
      const float4* hp = (const float4*)(h + (size_t)vd * 32);
#pragma unroll 1
      for (int kc = 0; kc < 8; kc++) {
        const float4 v = hp[kc];
        const float* w = w1t + kc * 128;
#pragma unroll
        for (int d = 0; d < 32; d++) acc[d] = fmaf(v.x, w[d], acc[d]);
#pragma unroll
        for (int d = 0; d < 32; d++) acc[d] = fmaf(v.y, w[32 + d], acc[d]);
#pragma unroll
        for (int d = 0; d < 32; d++) acc[d] = fmaf(v.z, w[64 + d], acc[d]);
#pragma unroll
        for (int d = 0; d < 32; d++) acc[d] = fmaf(v.w, w[96 + d], acc[d]);
      }
    }
    {
      const float4* hp = (const float4*)(h + (size_t)vs * 32);
#pragma unroll 1
      for (int kc = 0; kc < 8; kc++) {
        const float4 v = hp[kc];
        const float* w = w1t + 1024 + kc * 128;
#pragma unroll
        for (int d = 0; d < 32; d++) acc[d] = fmaf(v.x, w[d], acc[d]);
#pragma unroll
        for (int d = 0; d < 32; d++) acc[d] = fmaf(v.y, w[32 + d], acc[d]);
#pragma unroll
        for (int d = 0; d < 32; d++) acc[d] = fmaf(v.z, w[64 + d], acc[d]);
#pragma unroll
        for (int d = 0; d < 32; d++) acc[d] = fmaf(v.w, w[96 + d], acc[d]);
      }
    }
    uint4* mp = (uint4*)(mpre + (size_t)e * 16);
    mp[0] = make_uint4(pack2_bf16(acc[0], acc[1]), pack2_bf16(acc[2], acc[3]),
                       pack2_bf16(acc[4], acc[5]), pack2_bf16(acc[6], acc[7]));
    mp[1] = make_uint4(pack2_bf16(acc[8], acc[9]), pack2_bf16(acc[10], acc[11]),
                       pack2_bf16(acc[12], acc[13]), pack2_bf16(acc[14], acc[15]));
    mp[2] = make_uint4(pack2_bf16(acc[16], acc[17]), pack2_bf16(acc[18], acc[19]),
                       pack2_bf16(acc[20], acc[21]), pack2_bf16(acc[22], acc[23]));
    mp[3] = make_uint4(pack2_bf16(acc[24], acc[25]), pack2_bf16(acc[26], acc[27]),
                       pack2_bf16(acc[28], acc[29]), pack2_bf16(acc[30], acc[31]));
#pragma unroll
    for (int q = 0; q < 32; q++) { ssum[q] += acc[q]; ssq[q] = fmaf(acc[q], acc[q], ssq[q]); }
  }
  block_stats_reduce(ssum, ssq, stats);
}

// ---------- finalize: scale = g*rsqrt(var+eps), shift = b - mu*scale ----------
__global__ __launch_bounds__(1024) void k_finalize(const float* __restrict__ stats, int nblk, int E,
                                                   const float* __restrict__ g,
                                                   const float* __restrict__ bb,
                                                   float* __restrict__ ss) {
  const int t = threadIdx.x, q = t & 63, grp = t >> 6;  // 16 groups of 64
  double part = 0.0;
  for (int i = grp; i < nblk; i += 16) part += (double)stats[(size_t)i * 64 + q];
  __shared__ double red[16][64];
  red[grp][q] = part;
  __syncthreads();
  if (t < 64) {
    double s = 0.0;
#pragma unroll
    for (int i = 0; i < 16; i++) s += red[i][q];
    red[0][q] = s;
  }
  __syncthreads();
  if (t < 32) {
    double invE = 1.0 / (double)E;
    double mu = red[0][t] * invE;
    double var = red[0][32 + t] * invE - mu * mu;
    if (var < 0.0) var = 0.0;
    double sc = (double)g[t] / sqrt(var + 1e-5);
    ss[t] = (float)sc;
    ss[32 + t] = (float)((double)bb[t] - mu * sc);
  }
}

// ---------- pass B: m1 = relu(bn1(m_pre)); m_pre = m1 @ W2^T + b2 ; stats ----------
__global__ __launch_bounds__(256) void k_gemm2(
    uint32_t* __restrict__ mpre, const float* __restrict__ ss,
    const float* __restrict__ w2t, const float* __restrict__ b2,
    float* __restrict__ stats, int E) {
  float ssum[32], ssq[32];
#pragma unroll
  for (int q = 0; q < 32; q++) { ssum[q] = 0.f; ssq[q] = 0.f; }
  const int stride = gridDim.x * blockDim.x;
  for (int e = blockIdx.x * blockDim.x + threadIdx.x; e < E; e += stride) {
    uint4* mp = (uint4*)(mpre + (size_t)e * 16);
    uint4 r0 = mp[0], r1 = mp[1], r2 = mp[2], r3 = mp[3];
    uint32_t uu[16] = {r0.x, r0.y, r0.z, r0.w, r1.x, r1.y, r1.z, r1.w,
                       r2.x, r2.y, r2.z, r2.w, r3.x, r3.y, r3.z, r3.w};
    float m1[32];
#pragma unroll
    for (int p = 0; p < 16; p++) {
      m1[2 * p]     = __uint_as_float(uu[p] << 16);
      m1[2 * p + 1] = __uint_as_float(uu[p] & 0xffff0000u);
    }
#pragma unroll
    for (int d = 0; d < 32; d++) m1[d] = fmaxf(fmaf(m1[d], ss[d], ss[32 + d]), 0.f);
    float acc[32];
#pragma unroll
    for (int d = 0; d < 32; d++) acc[d] = b2[d];
#pragma unroll
    for (int k = 0; k < 32; k++) {
#pragma unroll
      for (int d = 0; d < 32; d++) acc[d] = fmaf(m1[k], w2t[k * 32 + d], acc[d]);
    }
    mp[0] = make_uint4(pack2_bf16(acc[0], acc[1]), pack2_bf16(acc[2], acc[3]),
                       pack2_bf16(acc[4], acc[5]), pack2_bf16(acc[6], acc[7]));
    mp[1] = make_uint4(pack2_bf16(acc[8], acc[9]), pack2_bf16(acc[10], acc[11]),
                       pack2_bf16(acc[12], acc[13]), pack2_bf16(acc[14], acc[15]));
    mp[2] = make_uint4(pack2_bf16(acc[16], acc[17]), pack2_bf16(acc[18], acc[19]),
                       pack2_bf16(acc[20], acc[21]), pack2_bf16(acc[22], acc[23]));
    mp[3] = make_uint4(pack2_bf16(acc[24], acc[25]), pack2_bf16(acc[26], acc[27]),
                       pack2_bf16(acc[28], acc[29]), pack2_bf16(acc[30], acc[31]));
#pragma unroll
    for (int q = 0; q < 32; q++) { ssum[q] += acc[q]; ssq[q] = fmaf(acc[q], acc[q], ssq[q]); }
  }
  block_stats_reduce(ssum, ssq, stats);
}

// ---------- pass C: h[dst] += relu(bn2(m_pre)) via atomics ----------
__global__ __launch_bounds__(256) void k_scatter(
    const uint32_t* __restrict__ mpre, const int* __restrict__ dst,
    const float* __restrict__ ss, float* __restrict__ h, int E) {
  const int tot = E * 32;
  const int stride = gridDim.x * blockDim.x;
  for (int t = blockIdx.x * blockDim.x + threadIdx.x; t < tot; t += stride) {
    const int e = t >> 5, d = t & 31;
    const uint32_t u = mpre[(size_t)e * 16 + (d >> 1)];
    float x = (d & 1) ? __uint_as_float(u & 0xffff0000u) : __uint_as_float(u << 16);
    float y = fmaxf(fmaf(x, ss[d], ss[32 + d]), 0.f);
    atomicAdd(h + (size_t)dst[e] * 32 + d, y);
  }
}

// ---------- readout ----------
__global__ __launch_bounds__(256) void k_initseg(unsigned* __restrict__ segmax,
                                                 float* __restrict__ segsum) {
  int t = blockIdx.x * 256 + threadIdx.x;
  if (t < NGRAPH) { segmax[t] = 0u; segsum[t] = 0.f; }
}

__global__ __launch_bounds__(256) void k_logits(
    const float* __restrict__ h, const int* __restrict__ cand, const int* __restrict__ batch,
    const float* __restrict__ wout, const float* __restrict__ bout,
    float* __restrict__ logits, int* __restrict__ seg, unsigned* __restrict__ segmax, int C) {
  int t = blockIdx.x * 256 + threadIdx.x;
  if (t >= C) return;
  int node = cand[t];
  const float4* hp = (const float4*)(h + (size_t)node * 32);
  float acc = bout[0];
#pragma unroll
  for (int kc = 0; kc < 8; kc++) {
    float4 v = hp[kc];
    acc = fmaf(v.x, wout[kc * 4 + 0], acc);
    acc = fmaf(v.y, wout[kc * 4 + 1], acc);
    acc = fmaf(v.z, wout[kc * 4 + 2], acc);
    acc = fmaf(v.w, wout[kc * 4 + 3], acc);
  }
  logits[t] = acc;
  int s = batch[node];
  seg[t] = s;
  unsigned o = __float_as_uint(acc);
  o ^= (o >> 31) ? 0xFFFFFFFFu : 0x80000000u;  // orderable mapping
  atomicMax(segmax + s, o);
}

static __device__ __forceinline__ float o2f(unsigned o) {
  o ^= (o & 0x80000000u) ? 0x80000000u : 0xFFFFFFFFu;
  return __uint_as_float(o);
}

__global__ __launch_bounds__(256) void k_expsum(const float* __restrict__ logits,
                                                const int* __restrict__ seg,
                                                const unsigned* __restrict__ segmax,
                                                float* __restrict__ segsum, int C) {
  int t = blockIdx.x * 256 + threadIdx.x;
  if (t >= C) return;
  int s = seg[t];
  float mx = o2f(segmax[s]);
  atomicAdd(segsum + s, expf(logits[t] - mx));
}

__global__ __launch_bounds__(256) void k_out(const float* __restrict__ logits,
                                             const int* __restrict__ seg,
                                             const unsigned* __restrict__ segmax,
                                             const float* __restrict__ segsum,
                                             float* __restrict__ out, int C) {
  int t = blockIdx.x * 256 + threadIdx.x;
  if (t >= C) return;
  int s = seg[t];
  out[t] = logits[t] - (o2f(segmax[s]) + logf(segsum[s]));
}

// ---------- launch ----------
extern "C" void kernel_launch(void* const* d_in, const int* in_sizes, int n_in,
                              void* d_out, int out_size, void* d_ws, size_t ws_size,
                              hipStream_t stream) {
  const float* x     = (const float*)d_in[0];
  const int*   eidx  = (const int*)d_in[1];
  const float* eattr = (const float*)d_in[2];
  const int*   cand  = (const int*)d_in[3];
  const int*   batch = (const int*)d_in[4];
  const float* wi    = (const float*)d_in[5];
  const float* bi    = (const float*)d_in[6];
  const float* w1    = (const float*)d_in[7];
  const float* b1    = (const float*)d_in[8];
  const float* g1    = (const float*)d_in[9];
  const float* bb1   = (const float*)d_in[10];
  const float* w2    = (const float*)d_in[11];
  const float* b2    = (const float*)d_in[12];
  const float* g2    = (const float*)d_in[13];
  const float* bb2   = (const float*)d_in[14];
  const float* wout  = (const float*)d_in[15];
  const float* bout  = (const float*)d_in[16];

  const int N = in_sizes[4];       // batch has N elements
  const int E = in_sizes[2];       // edge_attr has E elements
  const int C = in_sizes[3];
  const int* src  = eidx;
  const int* dstp = eidx + E;

  // workspace carve (total ~115.6 MB)
  char* ws = (char*)d_ws;
  size_t off = 0;
  auto carve = [&](size_t bytes) {
    void* p = ws + off;
    off = (off + bytes + 255) & ~(size_t)255;
    return p;
  };
  const int NBLK = 1024;
  uint32_t* mpre   = (uint32_t*)carve((size_t)E * 64);        // [E][32] bf16
  float*    h      = (float*)carve((size_t)N * 32 * 4);       // [N][32] f32
  float*    w1t    = (float*)carve(4 * 65 * 32 * 4);
  float*    w2t    = (float*)carve(4 * 32 * 32 * 4);
  float*    ss     = (float*)carve(64 * 4);                   // scale[32], shift[32]
  float*    stats  = (float*)carve((size_t)NBLK * 64 * 4);
  float*    logits = (float*)carve((size_t)C * 4);
  int*      seg    = (int*)carve((size_t)C * 4);
  unsigned* segmax = (unsigned*)carve(NGRAPH * 4);
  float*    segsum = (float*)carve(NGRAPH * 4);
  (void)ws_size; (void)n_in; (void)out_size;

  k_prep<<<49, 256, 0, stream>>>(w1, w2, w1t, w2t);
  k_init<<<(N * 32 + 255) / 256, 256, 0, stream>>>(x, wi, bi, h, N);

  for (int l = 0; l < 4; l++) {
    k_gemm1<<<NBLK, 256, 0, stream>>>(h, src, dstp, eattr, w1t + l * 2080, b1 + l * 32,
                                      mpre, stats, E);
    k_finalize<<<1, 1024, 0, stream>>>(stats, NBLK, E, g1 + l * 32, bb1 + l * 32, ss);
    k_gemm2<<<NBLK, 256, 0, stream>>>(mpre, ss, w2t + l * 1024, b2 + l * 32, stats, E);
    k_finalize<<<1, 1024, 0, stream>>>(stats, NBLK, E, g2 + l * 32, bb2 + l * 32, ss);
    k_scatter<<<4096, 256, 0, stream>>>(mpre, dstp, ss, h, E);
  }

  k_initseg<<<(NGRAPH + 255) / 256, 256, 0, stream>>>(segmax, segsum);
  k_logits<<<(C + 255) / 256, 256, 0, stream>>>(h, cand, batch, wout, bout,
                                                logits, seg, segmax, C);
  k_expsum<<<(C + 255) / 256, 256, 0, stream>>>(logits, seg, segmax, segsum, C);
  k_out<<<(C + 255) / 256, 256, 0, stream>>>(logits, seg, segmax, segsum, (float*)d_out, C);
}